// Round 1
// baseline (2113.098 us; speedup 1.0000x reference)
//
#include <hip/hip_runtime.h>
#include <stdint.h>

// Problem constants: B=4, L=4096, D=2048, I=5632
#define D_DIM 2048
#define I_DIM 5632
#define NTOK  16384
#define NTILE 65                  // worst-case 256-row M tiles (align256(n0)+n1 <= 16639)
#define MROWS (NTILE * 256)       // 16640
#define CHT   22                  // max M-tiles per chunk (65 = 22+22+21)
#define HROWS (CHT * 256)         // 5632 h rows

using f32x4  = __attribute__((ext_vector_type(4))) float;
using bf16x8 = __attribute__((ext_vector_type(8))) __bf16;
using u16x8  = __attribute__((ext_vector_type(8))) unsigned short;
using u16x4  = __attribute__((ext_vector_type(4))) unsigned short;
typedef unsigned short ushort;

__device__ __forceinline__ ushort f2bf(float f) {
  union { float f; unsigned int u; } v; v.f = f;
  unsigned int r = v.u + 0x7fffu + ((v.u >> 16) & 1u);   // RNE
  return (ushort)(r >> 16);
}

__device__ __forceinline__ void glds16(const void* g, void* l) {
  __builtin_amdgcn_global_load_lds(
      (__attribute__((address_space(1))) void*)(g),
      (__attribute__((address_space(3))) void*)(l),
      16, 0, 0);
}

// ---------------- mask scan ----------------
__global__ void count_kernel(const int* __restrict__ mask, int* __restrict__ cnt) {
  int i = blockIdx.x * 256 + threadIdx.x;
  if (i < NTOK && mask[i] == 0) atomicAdd(&cnt[0], 1);
}

__global__ void assign_kernel(const int* __restrict__ mask, int* __restrict__ cnt,
                              int* __restrict__ rowmap) {
  int i = blockIdx.x * 256 + threadIdx.x;
  if (i >= NTOK) return;
  int n0  = cnt[0];                 // count of und (mask==0) tokens
  int n0p = (n0 + 255) & ~255;      // 256-aligned so 256-row tiles are expert-uniform
  int row;
  if (mask[i] == 0) row = atomicAdd(&cnt[1], 1);
  else              row = n0p + atomicAdd(&cnt[2], 1);
  rowmap[row] = i;
}

// ---------------- fp32 -> bf16 flat cast (x) ----------------
__global__ __launch_bounds__(256) void cast_x_kernel(const float* __restrict__ in,
                                                     ushort* __restrict__ out) {
  int i = blockIdx.x * 256 + threadIdx.x;
  f32x4 v = ((const f32x4*)in)[i];
  u16x4 o;
#pragma unroll
  for (int j = 0; j < 4; j++) o[j] = f2bf(v[j]);
  ((u16x4*)out)[i] = o;
}

// ---------------- weight transpose+cast: fp32 (R,C) -> bf16 (C,R) ----------------
// phase >= 0: interleave gate(0)/up(1) rows at 16-granularity into a (2C, R) matrix:
//   irow = ((grow>>4)*2 + phase)*16 + (grow&15)
__global__ __launch_bounds__(256) void transpose_cast_kernel(
    const float* __restrict__ in, ushort* __restrict__ out, int R, int C, int phase) {
  __shared__ ushort s[64][72];
  int tC = blockIdx.x, tR = blockIdx.y;
  int tid = threadIdx.x;
  int r0 = tid >> 4;
  int c4 = (tid & 15) * 4;
  const float* src = in + (size_t)(tR * 64 + r0) * C + tC * 64 + c4;
#pragma unroll
  for (int rr = 0; rr < 64; rr += 16) {
    f32x4 v = *(const f32x4*)(src + (size_t)rr * C);
#pragma unroll
    for (int j = 0; j < 4; j++) s[r0 + rr][c4 + j] = f2bf(v[j]);
  }
  __syncthreads();
  int r8 = tid >> 3;
  int c8 = (tid & 7) * 8;
#pragma unroll
  for (int rr = 0; rr < 64; rr += 32) {
    int orow = r8 + rr;
    u16x8 v;
#pragma unroll
    for (int j = 0; j < 8; j++) v[j] = s[c8 + j][orow];
    int grow = tC * 64 + orow;
    int irow = (phase >= 0) ? (((grow >> 4) * 2 + phase) * 16 + (grow & 15)) : grow;
    *(u16x8*)(out + (size_t)irow * R + tR * 64 + c8) = v;
  }
}

// =====================================================================
// 256x256x64 8-phase counted-vmcnt GEMM template (m201-style, plain HIP)
// 512 threads = 8 waves (2M x 4N), per-wave 128x64 out, acc[8][4] f32x4.
// LDS: A[2][256*64] + B[2][256*64] bf16 = 128 KiB, XOR-swizzled chunks.
// Pipeline (per K-tile t, phases q0..q3):
//   q0: ds_read A-quad0 + all B frags; stage A-half0(t+1)  -> buf^1
//   q1: ds_read A-quad1;               stage A-half1(t+1)  -> buf^1
//   q2: ds_read A-quad2;               stage B-half0(t+2)  -> buf   (B(t) slots
//   q3: ds_read A-quad3;               stage B-half1(t+2)  -> buf    dead after q0)
//   each phase: barrier; lgkmcnt(0); setprio(1); 16 MFMA; setprio(0); barrier
//   q3 extra: s_waitcnt vmcnt(4) before trailing barrier -> retires A(t+1)+B(t+1),
//   leaves B(t+2)'s 4 loads in flight (never drains to 0 in the loop).
// =====================================================================

// ---------------- fused gate+up GEMM + swiglu ----------------
__global__ __launch_bounds__(512, 2)
void gateup8_kernel(const ushort* __restrict__ x, const int* __restrict__ rowmap,
                    const int* __restrict__ cnt, const ushort* __restrict__ wt,
                    ushort* __restrict__ h, int mbase) {
  __shared__ ushort sA[2][256 * 64];
  __shared__ ushort sB[2][256 * 64];

  const int bn = blockIdx.x, bm = blockIdx.y;
  const int gtile = mbase + bm;               // global 256-row M-tile
  const int tid  = threadIdx.x;
  const int lane = tid & 63, wave = tid >> 6;
  const int wm = wave >> 2, wn = wave & 3;    // 2 x 4 wave grid
  const int lrow = lane & 15, quad = lane >> 4;

  const int n0p = (cnt[0] + 255) & ~255;
  const int grp = (gtile * 256 >= n0p) ? 1 : 0;
  const ushort* W = wt + (size_t)grp * (2 * (size_t)I_DIM * D_DIM);  // interleaved 11264x2048

  // staging sources: g = j*512+tid; r=g>>3 (half-local row), c=g&7, cs = c^(r&7)
  const ushort* aSrc[2][2];
  const ushort* bSrc[2][2];
  int ldsOff[2][2];
#pragma unroll
  for (int hh = 0; hh < 2; hh++)
#pragma unroll
    for (int j = 0; j < 2; j++) {
      int g = j * 512 + tid;
      int r = g >> 3, c = g & 7;
      int cs = c ^ (r & 7);
      int tok = rowmap[gtile * 256 + hh * 128 + r];
      if (tok < 0) tok = 0;                   // gap rows: garbage, never scattered
      aSrc[hh][j] = x + (size_t)tok * D_DIM + cs * 8;
      bSrc[hh][j] = W + (size_t)(bn * 256 + hh * 128 + r) * D_DIM + cs * 8;
      ldsOff[hh][j] = hh * 8192 + (j * 512 + wave * 64) * 8;
    }

  f32x4 acc[8][4];
#pragma unroll
  for (int i = 0; i < 8; i++)
#pragma unroll
    for (int j = 0; j < 4; j++) acc[i][j] = (f32x4){0.f, 0.f, 0.f, 0.f};

  constexpr int NT = D_DIM / 64;   // 32

  // prologue: A(0) h0,h1; B(0) h0,h1; B(1) h0,h1  (12 loads; keep B(1) in flight)
#pragma unroll
  for (int hh = 0; hh < 2; hh++)
#pragma unroll
    for (int j = 0; j < 2; j++) glds16(aSrc[hh][j], &sA[0][ldsOff[hh][j]]);
#pragma unroll
  for (int hh = 0; hh < 2; hh++)
#pragma unroll
    for (int j = 0; j < 2; j++) glds16(bSrc[hh][j], &sB[0][ldsOff[hh][j]]);
#pragma unroll
  for (int hh = 0; hh < 2; hh++)
#pragma unroll
    for (int j = 0; j < 2; j++) glds16(bSrc[hh][j] + 64, &sB[1][ldsOff[hh][j]]);
  asm volatile("s_waitcnt vmcnt(4)" ::: "memory");
  __builtin_amdgcn_s_barrier();

  bf16x8 bfr[4][2];
  for (int t = 0; t < NT; ++t) {
    const int cur  = t & 1;
    const int kA   = ((t + 1 < NT) ? (t + 1) : (NT - 1)) * 64;  // clamp keeps counts invariant
    const int kB   = ((t + 2 < NT) ? (t + 2) : (NT - 1)) * 64;
    const int bufA = cur ^ 1;
#pragma unroll
    for (int q = 0; q < 4; ++q) {
      bf16x8 af[2][2];
#pragma unroll
      for (int mi = 0; mi < 2; mi++)
#pragma unroll
        for (int kk = 0; kk < 2; kk++) {
          int row = wm * 128 + (2 * q + mi) * 16 + lrow;
          int co  = ((kk * 4 + quad) ^ (lrow & 7)) * 8;
          af[mi][kk] = *(const bf16x8*)&sA[cur][row * 64 + co];
        }
      if (q == 0) {
#pragma unroll
        for (int j = 0; j < 4; j++)
#pragma unroll
          for (int kk = 0; kk < 2; kk++) {
            int row = wn * 64 + j * 16 + lrow;
            int co  = ((kk * 4 + quad) ^ (lrow & 7)) * 8;
            bfr[j][kk] = *(const bf16x8*)&sB[cur][row * 64 + co];
          }
      }
      if (q == 0)      { glds16(aSrc[0][0] + kA, &sA[bufA][ldsOff[0][0]]);
                         glds16(aSrc[0][1] + kA, &sA[bufA][ldsOff[0][1]]); }
      else if (q == 1) { glds16(aSrc[1][0] + kA, &sA[bufA][ldsOff[1][0]]);
                         glds16(aSrc[1][1] + kA, &sA[bufA][ldsOff[1][1]]); }
      else if (q == 2) { glds16(bSrc[0][0] + kB, &sB[cur][ldsOff[0][0]]);
                         glds16(bSrc[0][1] + kB, &sB[cur][ldsOff[0][1]]); }
      else             { glds16(bSrc[1][0] + kB, &sB[cur][ldsOff[1][0]]);
                         glds16(bSrc[1][1] + kB, &sB[cur][ldsOff[1][1]]); }

      __builtin_amdgcn_sched_barrier(0);
      __builtin_amdgcn_s_barrier();
      asm volatile("s_waitcnt lgkmcnt(0)" ::: "memory");
      __builtin_amdgcn_sched_barrier(0);
      __builtin_amdgcn_s_setprio(1);
#pragma unroll
      for (int mi = 0; mi < 2; mi++)
#pragma unroll
        for (int j = 0; j < 4; j++) {
          acc[2 * q + mi][j] = __builtin_amdgcn_mfma_f32_16x16x32_bf16(af[mi][0], bfr[j][0], acc[2 * q + mi][j], 0, 0, 0);
          acc[2 * q + mi][j] = __builtin_amdgcn_mfma_f32_16x16x32_bf16(af[mi][1], bfr[j][1], acc[2 * q + mi][j], 0, 0, 0);
        }
      __builtin_amdgcn_s_setprio(0);
      __builtin_amdgcn_sched_barrier(0);
      if (q == 3) asm volatile("s_waitcnt vmcnt(4)" ::: "memory");
      __builtin_amdgcn_s_barrier();
    }
  }

  // epilogue: interleaved N => acc[i][2p]=gate, acc[i][2p+1]=up, same lane/col
#pragma unroll
  for (int i = 0; i < 8; i++) {
    int rbase = bm * 256 + wm * 128 + i * 16 + quad * 4;   // chunk-local h row
#pragma unroll
    for (int pr = 0; pr < 2; pr++) {
      int icol = bn * 128 + wn * 32 + pr * 16 + lrow;
#pragma unroll
      for (int r = 0; r < 4; r++) {
        float g = acc[i][2 * pr][r];
        float u = acc[i][2 * pr + 1][r];
        float s = g / (1.f + __expf(-g));
        h[(size_t)(rbase + r) * I_DIM + icol] = f2bf(s * u);
      }
    }
  }
}

// ---------------- down GEMM + scatter (fp32 out) ----------------
__global__ __launch_bounds__(512, 2)
void down8_kernel(const ushort* __restrict__ h, const int* __restrict__ rowmap,
                  const int* __restrict__ cnt, const ushort* __restrict__ wdt,
                  float* __restrict__ out, int mbase) {
  __shared__ ushort sA[2][256 * 64];
  __shared__ ushort sB[2][256 * 64];

  const int bn = blockIdx.x, bm = blockIdx.y;
  const int gtile = mbase + bm;
  const int tid  = threadIdx.x;
  const int lane = tid & 63, wave = tid >> 6;
  const int wm = wave >> 2, wn = wave & 3;
  const int lrow = lane & 15, quad = lane >> 4;

  const int n0p = (cnt[0] + 255) & ~255;
  const int grp = (gtile * 256 >= n0p) ? 1 : 0;
  const ushort* W = wdt + (size_t)grp * ((size_t)D_DIM * I_DIM);

  const ushort* aSrc[2][2];
  const ushort* bSrc[2][2];
  int ldsOff[2][2];
#pragma unroll
  for (int hh = 0; hh < 2; hh++)
#pragma unroll
    for (int j = 0; j < 2; j++) {
      int g = j * 512 + tid;
      int r = g >> 3, c = g & 7;
      int cs = c ^ (r & 7);
      aSrc[hh][j] = h + (size_t)(bm * 256 + hh * 128 + r) * I_DIM + cs * 8;  // chunk-local
      bSrc[hh][j] = W + (size_t)(bn * 256 + hh * 128 + r) * I_DIM + cs * 8;
      ldsOff[hh][j] = hh * 8192 + (j * 512 + wave * 64) * 8;
    }

  f32x4 acc[8][4];
#pragma unroll
  for (int i = 0; i < 8; i++)
#pragma unroll
    for (int j = 0; j < 4; j++) acc[i][j] = (f32x4){0.f, 0.f, 0.f, 0.f};

  constexpr int NT = I_DIM / 64;   // 88

#pragma unroll
  for (int hh = 0; hh < 2; hh++)
#pragma unroll
    for (int j = 0; j < 2; j++) glds16(aSrc[hh][j], &sA[0][ldsOff[hh][j]]);
#pragma unroll
  for (int hh = 0; hh < 2; hh++)
#pragma unroll
    for (int j = 0; j < 2; j++) glds16(bSrc[hh][j], &sB[0][ldsOff[hh][j]]);
#pragma unroll
  for (int hh = 0; hh < 2; hh++)
#pragma unroll
    for (int j = 0; j < 2; j++) glds16(bSrc[hh][j] + 64, &sB[1][ldsOff[hh][j]]);
  asm volatile("s_waitcnt vmcnt(4)" ::: "memory");
  __builtin_amdgcn_s_barrier();

  bf16x8 bfr[4][2];
  for (int t = 0; t < NT; ++t) {
    const int cur  = t & 1;
    const int kA   = ((t + 1 < NT) ? (t + 1) : (NT - 1)) * 64;
    const int kB   = ((t + 2 < NT) ? (t + 2) : (NT - 1)) * 64;
    const int bufA = cur ^ 1;
#pragma unroll
    for (int q = 0; q < 4; ++q) {
      bf16x8 af[2][2];
#pragma unroll
      for (int mi = 0; mi < 2; mi++)
#pragma unroll
        for (int kk = 0; kk < 2; kk++) {
          int row = wm * 128 + (2 * q + mi) * 16 + lrow;
          int co  = ((kk * 4 + quad) ^ (lrow & 7)) * 8;
          af[mi][kk] = *(const bf16x8*)&sA[cur][row * 64 + co];
        }
      if (q == 0) {
#pragma unroll
        for (int j = 0; j < 4; j++)
#pragma unroll
          for (int kk = 0; kk < 2; kk++) {
            int row = wn * 64 + j * 16 + lrow;
            int co  = ((kk * 4 + quad) ^ (lrow & 7)) * 8;
            bfr[j][kk] = *(const bf16x8*)&sB[cur][row * 64 + co];
          }
      }
      if (q == 0)      { glds16(aSrc[0][0] + kA, &sA[bufA][ldsOff[0][0]]);
                         glds16(aSrc[0][1] + kA, &sA[bufA][ldsOff[0][1]]); }
      else if (q == 1) { glds16(aSrc[1][0] + kA, &sA[bufA][ldsOff[1][0]]);
                         glds16(aSrc[1][1] + kA, &sA[bufA][ldsOff[1][1]]); }
      else if (q == 2) { glds16(bSrc[0][0] + kB, &sB[cur][ldsOff[0][0]]);
                         glds16(bSrc[0][1] + kB, &sB[cur][ldsOff[0][1]]); }
      else             { glds16(bSrc[1][0] + kB, &sB[cur][ldsOff[1][0]]);
                         glds16(bSrc[1][1] + kB, &sB[cur][ldsOff[1][1]]); }

      __builtin_amdgcn_sched_barrier(0);
      __builtin_amdgcn_s_barrier();
      asm volatile("s_waitcnt lgkmcnt(0)" ::: "memory");
      __builtin_amdgcn_sched_barrier(0);
      __builtin_amdgcn_s_setprio(1);
#pragma unroll
      for (int mi = 0; mi < 2; mi++)
#pragma unroll
        for (int j = 0; j < 4; j++) {
          acc[2 * q + mi][j] = __builtin_amdgcn_mfma_f32_16x16x32_bf16(af[mi][0], bfr[j][0], acc[2 * q + mi][j], 0, 0, 0);
          acc[2 * q + mi][j] = __builtin_amdgcn_mfma_f32_16x16x32_bf16(af[mi][1], bfr[j][1], acc[2 * q + mi][j], 0, 0, 0);
        }
      __builtin_amdgcn_s_setprio(0);
      __builtin_amdgcn_sched_barrier(0);
      if (q == 3) asm volatile("s_waitcnt vmcnt(4)" ::: "memory");
      __builtin_amdgcn_s_barrier();
    }
  }

  // epilogue: scatter fp32 rows to out[token]
#pragma unroll
  for (int i = 0; i < 8; i++) {
    int grow = gtile * 256 + wm * 128 + i * 16 + quad * 4;
#pragma unroll
    for (int r = 0; r < 4; r++) {
      int tok = rowmap[grow + r];
      if (tok < 0) continue;
#pragma unroll
      for (int j = 0; j < 4; j++) {
        int col = bn * 256 + wn * 64 + j * 16 + lrow;
        out[(size_t)tok * D_DIM + col] = acc[i][j][r];
      }
    }
  }
}

extern "C" void kernel_launch(void* const* d_in, const int* in_sizes, int n_in,
                              void* d_out, int out_size, void* d_ws, size_t ws_size,
                              hipStream_t stream) {
  const float* x   = (const float*)d_in[0];    // hidden_states fp32 (16384, 2048)
  const int* mask  = (const int*)d_in[1];      // gen_token_mask int32 (16384)
  const float* ug  = (const float*)d_in[2];    // und_gate fp32 (D,I)
  const float* uu  = (const float*)d_in[3];    // und_up   (D,I)
  const float* ud  = (const float*)d_in[4];    // und_down (I,D)
  const float* gg  = (const float*)d_in[5];    // gen_gate (D,I)
  const float* gu  = (const float*)d_in[6];    // gen_up   (D,I)
  const float* gd  = (const float*)d_in[7];    // gen_down (I,D)
  float* out = (float*)d_out;

  // ws layout (~269.0 MB, down from 299.3 MB):
  //   [0,256) counters | [256, +66560) rowmap[16640]
  //   xb:  bf16 x (16384,2048)                      67,108,864 B
  //   wt:  [undGU interleaved 11264x2048][genGU interleaved][undDown 2048x5632][genDown]
  //                                                138,412,032 B
  //   h:   bf16 (5632, 5632)                        63,438,848 B
  char* ws = (char*)d_ws;
  int* cnt    = (int*)ws;
  int* rowmap = (int*)(ws + 256);
  ushort* xb  = (ushort*)(ws + 256 + MROWS * sizeof(int));
  const size_t WSZ = (size_t)I_DIM * D_DIM;     // 11,534,336 elems
  ushort* wt   = xb + (size_t)NTOK * D_DIM;
  ushort* hbuf = wt + 6 * WSZ;

  hipMemsetAsync(cnt, 0, 256, stream);
  hipMemsetAsync(rowmap, 0xFF, MROWS * sizeof(int), stream);   // -1
  count_kernel<<<64, 256, 0, stream>>>(mask, cnt);
  assign_kernel<<<64, 256, 0, stream>>>(mask, cnt, rowmap);

  cast_x_kernel<<<(NTOK * D_DIM / 4) / 256, 256, 0, stream>>>(x, xb);

  // gate/up -> interleaved (2I, D); down -> (D, I)
  transpose_cast_kernel<<<dim3(88, 32), 256, 0, stream>>>(ug, wt,           2048, 5632, 0);
  transpose_cast_kernel<<<dim3(88, 32), 256, 0, stream>>>(uu, wt,           2048, 5632, 1);
  transpose_cast_kernel<<<dim3(88, 32), 256, 0, stream>>>(gg, wt + 2 * WSZ, 2048, 5632, 0);
  transpose_cast_kernel<<<dim3(88, 32), 256, 0, stream>>>(gu, wt + 2 * WSZ, 2048, 5632, 1);
  transpose_cast_kernel<<<dim3(32, 88), 256, 0, stream>>>(ud, wt + 4 * WSZ, 5632, 2048, -1);
  transpose_cast_kernel<<<dim3(32, 88), 256, 0, stream>>>(gd, wt + 5 * WSZ, 5632, 2048, -1);

  // chunked M (256-row tiles): 22 + 22 + 21 = 65
  const int bases[3] = {0, 22, 44};
  const int sizes[3] = {22, 22, 21};
  for (int c = 0; c < 3; c++) {
    gateup8_kernel<<<dim3(I_DIM * 2 / 256, sizes[c]), 512, 0, stream>>>(
        xb, rowmap, cnt, wt, hbuf, bases[c]);
    down8_kernel<<<dim3(D_DIM / 256, sizes[c]), 512, 0, stream>>>(
        hbuf, rowmap, cnt, wt + 4 * WSZ, out, bases[c]);
  }
}